// Round 8
// baseline (297.216 us; speedup 1.0000x reference)
//
#include <hip/hip_runtime.h>
#include <hip/hip_bf16.h>

#define BATCH   16
#define NELEM   131072
#define PRE_NMS 2048
#define POST_NMS 512
#define NBKT    8192
#define NCH     32
#define NTHR    512
#define NBIN    16
#define BINCAP  96
#define OVCAP   512
#define CAP     4096

// ws layout (bytes):
// hist [0,512K) | fillg [512K,1M) | cutb @1M | binstartg [1048640,1572928) | candg [1572928,2097216)
#define OFF_FILL  524288
#define OFF_CUTB  1048576
#define OFF_BST   1048640
#define OFF_CAND  1572928

typedef unsigned long long u64;
typedef unsigned int u32;

__device__ __forceinline__ u32 okey_f32(float f) {
  u32 u = __float_as_uint(f);
  return (u & 0x80000000u) ? ~u : (u | 0x80000000u);  // ascending uint == ascending float
}

__global__ __launch_bounds__(256) void hist_kernel(const float* __restrict__ obj,
                                                   u32* __restrict__ hist) {
  int b = blockIdx.x >> 4, q = blockIdx.x & 15;   // 16 blocks per image
  __shared__ u32 lh[NBKT];
  for (int i = threadIdx.x; i < NBKT; i += 256) lh[i] = 0u;
  __syncthreads();
  const float4* p4 = (const float4*)(obj + (size_t)b * NELEM + (size_t)q * 8192);
#pragma unroll
  for (int k = 0; k < 8; ++k) {
    float4 v = p4[threadIdx.x + k * 256];
    atomicAdd(&lh[okey_f32(v.x) >> 19], 1u);
    atomicAdd(&lh[okey_f32(v.y) >> 19], 1u);
    atomicAdd(&lh[okey_f32(v.z) >> 19], 1u);
    atomicAdd(&lh[okey_f32(v.w) >> 19], 1u);
  }
  __syncthreads();
  u32* gh = hist + (size_t)b * NBKT;
  for (int i = threadIdx.x; i < NBKT; i += 256) {
    u32 c = lh[i];
    if (c) atomicAdd(&gh[i], c);
  }
}

// suffix-scan the histogram; write cut bucket AND per-bucket segment starts
__global__ void cut_kernel(const u32* __restrict__ hist, u32* __restrict__ cutb,
                           u32* __restrict__ bstg) {
  int b = blockIdx.x, t = threadIdx.x;
  const u32* h = hist + (size_t)b * NBKT;
  u32* bst = bstg + (size_t)b * NBKT;
  u32 loc[32];
  u32 s = 0;
#pragma unroll
  for (int k = 0; k < 32; ++k) { loc[k] = h[t * 32 + k]; s += loc[k]; }
  __shared__ u32 sa[256], sb[256];
  sa[t] = s;
  __syncthreads();
  u32* cur = sa; u32* nxt = sb;
  for (int d = 1; d < 256; d <<= 1) {           // inclusive suffix scan
    nxt[t] = cur[t] + ((t + d < 256) ? cur[t + d] : 0u);
    __syncthreads();
    u32* tmp = cur; cur = nxt; nxt = tmp;
  }
  u32 above = cur[t] - s;
  u32 run = above;
#pragma unroll
  for (int k = 31; k >= 0; --k) {               // high -> low buckets
    u32 prev = run; run += loc[k];
    bst[t * 32 + k] = prev;                     // segment start = count strictly above
    if (prev < PRE_NMS && run >= PRE_NMS) cutb[b] = (u32)(t * 32 + k);
  }
}

// scatter candidates (bucket >= cut) directly into bucket-ordered global array
__global__ __launch_bounds__(256) void collect_kernel(
    const float* __restrict__ obj, const u32* __restrict__ cutb,
    const u32* __restrict__ bstg, u32* __restrict__ fillg, u64* __restrict__ candg) {
  int b = blockIdx.x >> 5, seg = blockIdx.x & 31;
  u32 cut = cutb[b];
  const u32* bst = bstg + (size_t)b * NBKT;
  u32* fil = fillg + (size_t)b * NBKT;
  u64* cg = candg + (size_t)b * CAP;
  const float4* p4 = (const float4*)(obj + (size_t)b * NELEM + (size_t)seg * 4096);
#pragma unroll
  for (int k = 0; k < 4; ++k) {
    float4 v = p4[threadIdx.x + k * 256];
    int e0 = seg * 4096 + 4 * (threadIdx.x + k * 256);
    float vv[4] = {v.x, v.y, v.z, v.w};
#pragma unroll
    for (int j = 0; j < 4; ++j) {
      u32 ok = okey_f32(vv[j]);
      u32 bkt = ok >> 19;
      if (bkt >= cut) {
        u32 pos = bst[bkt] + atomicAdd(&fil[bkt], 1u);
        if (pos < CAP) cg[pos] = ((u64)(~ok) << 32) | (u32)(e0 + j);
      }
    }
  }
}

// EXACT f32-only replacement for: fdiv_rn(max(i,0), max(uni,1e-6)) > 0.5
// (proof in R3/R4: i > 0.5f*max(uni,1e-6) is bit-identical to the reference)
__device__ __forceinline__ bool iou_gt(float2 a, float wa, float2 b, float wb) {
  float i = __fsub_rn(fminf(a.y, b.y), fmaxf(a.x, b.x));
  float uni = __fsub_rn(__fadd_rn(wa, wb), i);
  return i > __fmul_rn(0.5f, fmaxf(uni, 1e-6f));
}

__device__ __forceinline__ float2 decode_one(const float2* __restrict__ d2,
                                             const float2* __restrict__ a2,
                                             size_t base, u32 idx, float img) {
  float2 dd = d2[base + idx];
  float2 aa = a2[base + idx];
  float aw = __fsub_rn(aa.y, aa.x);
  float ac = __fadd_rn(aa.x, __fmul_rn(0.5f, aw));
  float dw = fminf(dd.y, 4.0f);
  float pc = __fadd_rn(__fmul_rn(dd.x, aw), ac);
  float pw = __fmul_rn(expf(dw), aw);
  float hx = __fmul_rn(0.5f, pw);
  float x1 = fminf(fmaxf(__fsub_rn(pc, hx), 0.0f), img);
  float x2 = fminf(fmaxf(__fadd_rn(pc, hx), 0.0f), img);
  return make_float2(x1, x2);
}

// rank-scatter (replaces sort) + decode + single-wave pull-NMS chain + output
__global__ __launch_bounds__(NTHR) void final_kernel(
    const float* __restrict__ delta, const float* __restrict__ anchor,
    const int* __restrict__ imgp, const u32* __restrict__ cutb,
    const u32* __restrict__ bstg, const u32* __restrict__ fillg,
    const u64* __restrict__ candg, float* __restrict__ out) {
  __shared__ u64 keys[CAP];            // 32 KB; later: rowmL=keys[0..2048), bins=keys[2048..4096)
  __shared__ u32 gpos[PRE_NMS];        // 8 KB sorted candidate indices
  __shared__ float2 box[PRE_NMS];      // 16 KB
  __shared__ u32 keepw[NCH * 2];
  __shared__ u32 wpre[65];
  __shared__ u32 bcnt[NBIN];
  __shared__ u32 ovcnt;

  u64* rowmL = keys;                                    // [32][64] u64
  float2* keptbin = (float2*)(keys + 2048);             // [NBIN][BINCAP]
  float2* ovlist  = (float2*)(keys + 2048 + NBIN * BINCAP / 1 * 1 + 0) ;  // fixed below
  ovlist = (float2*)(keys + 2048 + (NBIN * BINCAP));    // 2048+1536=3584 .. 4096 (512 float2)

  int b = blockIdx.x, t = threadIdx.x;
  int wv = t >> 6, lane = t & 63;

  u32 cut = cutb[b];
  const u32* bst = bstg + (size_t)b * NBKT;
  const u32* fil = fillg + (size_t)b * NBKT;
  u32 S = bst[cut];
  u32 endTotal = S + fil[cut];
  if (endTotal > CAP) endTotal = CAP;

  const u64* cg = candg + (size_t)b * CAP;
  for (u32 p = t; p < CAP; p += NTHR)
    keys[p] = (p < endTotal) ? cg[p] : ~0ull;
  __syncthreads();

  // exact rank within bucket segment (keys distinct: idx tiebreak embedded)
  for (u32 p = t; p < endTotal; p += NTHR) {
    u64 k = keys[p];
    u32 bkt = (~(u32)(k >> 32)) >> 19;
    u32 s = bst[bkt];
    u32 e = s + fil[bkt];
    if (e > endTotal) e = endTotal;
    u32 cnt = 0;
    for (u32 q = s; q < e; ++q) cnt += (keys[q] < k) ? 1u : 0u;
    u32 r = s + cnt;
    if (r < PRE_NMS) gpos[r] = (u32)k;
  }
  __syncthreads();

  // decode + clip: thread owns candidates t + 512r (chunk wv + 8r)
  int iv = imgp[0];
  float img = (iv > 0 && iv < 1000000) ? (float)iv : __int_as_float(iv);
  const float2* d2 = (const float2*)delta;
  const float2* a2 = (const float2*)anchor;
  size_t base = (size_t)b * NELEM;
  float2 bx0 = decode_one(d2, a2, base, gpos[t], img);
  float2 bx1 = decode_one(d2, a2, base, gpos[t + 512], img);
  float2 bx2 = decode_one(d2, a2, base, gpos[t + 1024], img);
  float2 bx3 = decode_one(d2, a2, base, gpos[t + 1536], img);
  box[t] = bx0; box[t + 512] = bx1; box[t + 1024] = bx2; box[t + 1536] = bx3;
  __syncthreads();   // box complete; keys region free for rowmL overlay

  // in-chunk 64x64 exact adjacency rows -> rowmL (keys[0..2048))
  {
    float w0 = __fsub_rn(bx0.y, bx0.x), w1 = __fsub_rn(bx1.y, bx1.x);
    float w2 = __fsub_rn(bx2.y, bx2.x), w3 = __fsub_rn(bx3.y, bx3.x);
    u64 m0 = 0, m1 = 0, m2 = 0, m3 = 0;
    int c0 = wv * 64, c1 = (wv + 8) * 64, c2 = (wv + 16) * 64, c3 = (wv + 24) * 64;
    for (int j = 0; j < 64; ++j) {
      float2 q0 = box[c0 + j], q1 = box[c1 + j], q2 = box[c2 + j], q3 = box[c3 + j];
      if ((j != lane) & iou_gt(bx0, w0, q0, __fsub_rn(q0.y, q0.x))) m0 |= 1ull << j;
      if ((j != lane) & iou_gt(bx1, w1, q1, __fsub_rn(q1.y, q1.x))) m1 |= 1ull << j;
      if ((j != lane) & iou_gt(bx2, w2, q2, __fsub_rn(q2.y, q2.x))) m2 |= 1ull << j;
      if ((j != lane) & iou_gt(bx3, w3, q3, __fsub_rn(q3.y, q3.x))) m3 |= 1ull << j;
    }
    rowmL[(wv)      * 64 + lane] = m0;
    rowmL[(wv + 8)  * 64 + lane] = m1;
    rowmL[(wv + 16) * 64 + lane] = m2;
    rowmL[(wv + 24) * 64 + lane] = m3;
  }
  __syncthreads();

  // ---- single-wave greedy NMS chain: zero barriers, pull-based suppression ----
  if (wv == 0) {
    u64 M[NCH];
#pragma unroll
    for (int c = 0; c < NCH; ++c) M[c] = rowmL[c * 64 + lane];
    if (lane < NBIN) bcnt[lane] = 0u;
    if (lane == 16) ovcnt = 0u;
    float inv = (float)NBIN / img;
    float maxHW = 0.0f;
    u32 Lcnt = 0;
#pragma unroll
    for (int c = 0; c < NCH; ++c) {
      float2 me = box[c * 64 + lane];
      float wme = __fsub_rn(me.y, me.x);
      float cme = __fmul_rn(0.5f, __fadd_rn(me.x, me.y));
      // pull: suppressor kb satisfies |c_kb - c_me| < w_kb/2 <= maxHW (exact, R8 proof)
      float R = __fadd_rn(maxHW, 0.3f);
      int blo = (int)(__fsub_rn(cme, R) * inv); blo = blo < 0 ? 0 : (blo > NBIN - 1 ? NBIN - 1 : blo);
      int bhi = (int)(__fadd_rn(cme, R) * inv); bhi = bhi < 0 ? 0 : (bhi > NBIN - 1 ? NBIN - 1 : bhi);
      bool sup = false;
      for (int bb = blo; bb <= bhi; ++bb) {
        u32 n = bcnt[bb]; if (n > BINCAP) n = BINCAP;
        for (u32 i = 0; i < n; ++i) {
          float2 kb = keptbin[bb * BINCAP + i];
          sup = sup | iou_gt(me, wme, kb, __fsub_rn(kb.y, kb.x));
        }
      }
      {
        u32 n = ovcnt;
        for (u32 i = 0; i < n; ++i) {
          float2 kb = ovlist[i];
          sup = sup | iou_gt(me, wme, kb, __fsub_rn(kb.y, kb.x));
        }
      }
      u64 sb = __ballot(sup);
      u64 rem = ~sb;
      u64 kept = 0ull;
      u32 mlo = (u32)M[c], mhi = (u32)(M[c] >> 32);
      while (rem) {                      // visit kept candidates only
        int i = __builtin_ctzll(rem);
        kept |= 1ull << i;
        u32 rlo = (u32)__builtin_amdgcn_readlane((int)mlo, i);
        u32 rhi = (u32)__builtin_amdgcn_readlane((int)mhi, i);
        u64 row = ((u64)rhi << 32) | (u64)rlo;
        rem &= ~(row | (1ull << i));
      }
      if (lane == 0) {
        keepw[c * 2]     = (u32)kept;
        keepw[c * 2 + 1] = (u32)(kept >> 32);
      }
      Lcnt += (u32)__popcll(kept);
      bool amKept = (kept >> lane) & 1ull;
      if (amKept) {                      // insert into center bin (overflow exact)
        int bin = (int)(cme * inv); bin = bin < 0 ? 0 : (bin > NBIN - 1 ? NBIN - 1 : bin);
        u32 slot = atomicAdd(&bcnt[bin], 1u);
        if (slot < BINCAP) keptbin[bin * BINCAP + slot] = me;
        else { u32 os = atomicAdd(&ovcnt, 1u); if (os < OVCAP) ovlist[os] = me; }
      }
      float hw = amKept ? __fmul_rn(0.5f, wme) : 0.0f;
#pragma unroll
      for (int d = 1; d < 64; d <<= 1) hw = fmaxf(hw, __shfl_xor(hw, d));
      maxHW = fmaxf(maxHW, hw);
      if (Lcnt >= POST_NMS) {            // outputs determined; zero undecided chunks
        int w2 = c * 2 + 2 + lane;
        if (w2 < NCH * 2) keepw[w2] = 0u;
        break;
      }
    }
  }
  __syncthreads();

  // stable partition: kept first (ascending), then unkept (ascending)
  if (wv == 0) {
    u32 wvv = keepw[lane];
    u32 pc = __popc(wvv);
    u32 inc = pc;
    for (int d = 1; d < 64; d <<= 1) {
      u32 v = __shfl_up(inc, d);
      if (lane >= d) inc += v;
    }
    wpre[lane] = inc - pc;
    if (lane == 63) wpre[64] = inc;
  }
  __syncthreads();
  u32 K = wpre[64];
  size_t selOff = (size_t)BATCH * POST_NMS * 2;
  size_t valOff = selOff + (size_t)BATCH * POST_NMS;
#pragma unroll
  for (int r = 0; r < 4; ++r) {
    int p = t + NTHR * r;
    u32 w = p >> 5, bit = p & 31;
    u32 wvv = keepw[w];
    bool kp = (wvv >> bit) & 1u;
    u32 kpref = wpre[w] + __popc(wvv & ((1u << bit) - 1u));
    u32 rr = kp ? kpref : (K + ((u32)p - kpref));
    if (rr < POST_NMS) {
      float2 bxo = kp ? box[p] : make_float2(0.0f, 0.0f);
      size_t ob = (size_t)b * POST_NMS + rr;
      out[ob * 2 + 0] = bxo.x;
      out[ob * 2 + 1] = bxo.y;
      out[selOff + ob] = (float)p;
      out[valOff + ob] = kp ? 1.0f : 0.0f;
    }
  }
}

extern "C" void kernel_launch(void* const* d_in, const int* in_sizes, int n_in,
                              void* d_out, int out_size, void* d_ws, size_t ws_size,
                              hipStream_t stream) {
  const float* obj    = (const float*)d_in[0];
  const float* delta  = (const float*)d_in[1];
  const float* anchor = (const float*)d_in[2];
  const int*   imgp   = (const int*)d_in[3];
  float* out = (float*)d_out;

  unsigned char* w = (unsigned char*)d_ws;
  u32* hist  = (u32*)(w);
  u32* fillg = (u32*)(w + OFF_FILL);
  u32* cutb  = (u32*)(w + OFF_CUTB);
  u32* bstg  = (u32*)(w + OFF_BST);
  u64* candg = (u64*)(w + OFF_CAND);

  // zero hist + fillg every call (ws not re-poisoned between replays)
  hipMemsetAsync(w, 0, OFF_CUTB, stream);

  hist_kernel<<<dim3(256), dim3(256), 0, stream>>>(obj, hist);
  cut_kernel<<<dim3(BATCH), dim3(256), 0, stream>>>(hist, cutb, bstg);
  collect_kernel<<<dim3(512), dim3(256), 0, stream>>>(obj, cutb, bstg, fillg, candg);
  final_kernel<<<dim3(BATCH), dim3(NTHR), 0, stream>>>(delta, anchor, imgp, cutb,
                                                       bstg, fillg, candg, out);
}

// Round 9
// 125.176 us; speedup vs baseline: 2.3744x; 2.3744x over previous
//
#include <hip/hip_runtime.h>
#include <hip/hip_bf16.h>

#define BATCH   16
#define NELEM   131072
#define PRE_NMS 2048
#define POST_NMS 512
#define NBKT    8192
#define NCH     32
#define NSB     256
#define FTHR    512

// ws: hist [0,512K) | cntA @524288 | cntB @524352 | cutb @524416 |
// candA [524544,786688) | candB [786688,1048832) | sortA [1048832,1310976)
#define OFF_CNTA  524288
#define OFF_CNTB  524352
#define OFF_CUT   524416
#define OFF_CANDA 524544
#define OFF_CANDB 786688
#define OFF_SORT  1048832

typedef unsigned long long u64;
typedef unsigned int u32;
typedef unsigned short u16;

__device__ __forceinline__ u32 okey_f32(float f) {
  u32 u = __float_as_uint(f);
  return (u & 0x80000000u) ? ~u : (u | 0x80000000u);  // ascending uint == ascending float
}

__global__ __launch_bounds__(256) void hist_kernel(const float* __restrict__ obj,
                                                   u32* __restrict__ hist) {
  int b = blockIdx.x >> 4, q = blockIdx.x & 15;   // 16 blocks per image
  __shared__ u32 lh[NBKT];
  for (int i = threadIdx.x; i < NBKT; i += 256) lh[i] = 0u;
  __syncthreads();
  const float4* p4 = (const float4*)(obj + (size_t)b * NELEM + (size_t)q * 8192);
#pragma unroll
  for (int k = 0; k < 8; ++k) {
    float4 v = p4[threadIdx.x + k * 256];
    atomicAdd(&lh[okey_f32(v.x) >> 19], 1u);
    atomicAdd(&lh[okey_f32(v.y) >> 19], 1u);
    atomicAdd(&lh[okey_f32(v.z) >> 19], 1u);
    atomicAdd(&lh[okey_f32(v.w) >> 19], 1u);
  }
  __syncthreads();
  u32* gh = hist + (size_t)b * NBKT;
  for (int i = threadIdx.x; i < NBKT; i += 256) {
    u32 c = lh[i];
    if (c) atomicAdd(&gh[i], c);
  }
}

__global__ void cut_kernel(const u32* __restrict__ hist, u32* __restrict__ cutb) {
  int b = blockIdx.x, t = threadIdx.x;
  const u32* h = hist + (size_t)b * NBKT;
  u32 loc[32];
  u32 s = 0;
#pragma unroll
  for (int k = 0; k < 32; ++k) { loc[k] = h[t * 32 + k]; s += loc[k]; }
  __shared__ u32 sa[256], sb[256];
  sa[t] = s;
  __syncthreads();
  u32* cur = sa; u32* nxt = sb;
  for (int d = 1; d < 256; d <<= 1) {           // inclusive suffix scan
    nxt[t] = cur[t] + ((t + d < 256) ? cur[t + d] : 0u);
    __syncthreads();
    u32* tmp = cur; cur = nxt; nxt = tmp;
  }
  u32 above = cur[t] - s;
  u32 run = above;
#pragma unroll
  for (int k = 31; k >= 0; --k) {               // high -> low buckets
    u32 prev = run; run += loc[k];
    // at chosen bucket: S(strictly above)=prev < 2048, S+T = run >= 2048
    if (prev < PRE_NMS && run >= PRE_NMS) cutb[b] = (u32)(t * 32 + k);
  }
}

__global__ void collect_kernel(const float* __restrict__ obj, const u32* __restrict__ cutb,
                               u32* __restrict__ cntA, u32* __restrict__ cntB,
                               u64* __restrict__ candA, u64* __restrict__ candB) {
  int b = blockIdx.x >> 5, seg = blockIdx.x & 31;
  __shared__ u64 buf[4096];                  // A grows up, B grows down
  __shared__ u32 lA, lB, gA, gB;
  if (threadIdx.x == 0) { lA = 0u; lB = 0u; }
  __syncthreads();
  u32 c = cutb[b];
  const float* p = obj + (size_t)b * NELEM + (size_t)seg * 4096;
#pragma unroll
  for (int k = 0; k < 16; ++k) {
    int li = threadIdx.x + k * 256;
    u32 ok = okey_f32(p[li]);
    u32 bkt = ok >> 19;
    if (bkt >= c) {
      u64 key = ((u64)(~ok) << 32) | (u32)(seg * 4096 + li);
      if (bkt > c) buf[atomicAdd(&lA, 1u)] = key;
      else         buf[4095u - atomicAdd(&lB, 1u)] = key;
    }
  }
  __syncthreads();
  if (threadIdx.x == 0) { gA = atomicAdd(&cntA[b], lA); gB = atomicAdd(&cntB[b], lB); }
  __syncthreads();
  u64* cbA = candA + (size_t)b * PRE_NMS;
  u64* cbB = candB + (size_t)b * PRE_NMS;
  for (u32 i = threadIdx.x; i < lA; i += 256) {
    u32 d = gA + i; if (d < 2048u) cbA[d] = buf[i];
  }
  for (u32 i = threadIdx.x; i < lB; i += 256) {
    u32 d = gB + i; if (d < 2048u) cbB[d] = buf[4095u - i];
  }
}

// EXACT f32-only replacement for: fdiv_rn(max(i,0), max(uni,1e-6)) > 0.5
// (proof in R3/R4: i > 0.5f*max(uni,1e-6) is bit-identical to the reference)
__device__ __forceinline__ bool iou_gt(float2 a, float wa, float2 b, float wb) {
  float i = __fsub_rn(fminf(a.y, b.y), fmaxf(a.x, b.x));
  float uni = __fsub_rn(__fadd_rn(wa, wb), i);
  return i > __fmul_rn(0.5f, fmaxf(uni, 1e-6f));
}

__device__ __forceinline__ float2 decode_one(const float2* __restrict__ d2,
                                             const float2* __restrict__ a2,
                                             size_t base, u32 idx, float img) {
  float2 dd = d2[base + idx];
  float2 aa = a2[base + idx];
  float aw = __fsub_rn(aa.y, aa.x);
  float ac = __fadd_rn(aa.x, __fmul_rn(0.5f, aw));
  float dw = fminf(dd.y, 4.0f);
  float pc = __fadd_rn(__fmul_rn(dd.x, aw), ac);
  float pw = __fmul_rn(expf(dw), aw);
  float hx = __fmul_rn(0.5f, pw);
  float x1 = fminf(fmaxf(__fsub_rn(pc, hx), 0.0f), img);
  float x2 = fminf(fmaxf(__fadd_rn(pc, hx), 0.0f), img);
  return make_float2(x1, x2);
}

__device__ __forceinline__ u64 shflx64(u64 v, int j) {
  int lo = __shfl_xor((int)(u32)v, j, 64);
  int hi = __shfl_xor((int)(u32)(v >> 32), j, 64);
  return ((u64)(u32)hi << 32) | (u64)(u32)lo;
}

__device__ __forceinline__ void wave_ce(u64& e, int i, int k, int j, int lane) {
  u64 o = shflx64(e, j);
  bool low = ((lane & j) == 0);
  bool up = ((i & k) == 0);
  u64 mn = (o < e) ? o : e;
  u64 mx = (o < e) ? e : o;
  e = (low == up) ? mn : mx;
}

__device__ __forceinline__ void reg_ce(u64& a, u64& b, bool up) {
  u64 mn = (b < a) ? b : a;
  u64 mx = (b < a) ? a : b;
  a = up ? mn : mx;
  b = up ? mx : mn;
}

__device__ __forceinline__ void lds_ce(u64& e, u64 o, bool low, bool up) {
  u64 mn = (o < e) ? o : e;
  u64 mx = (o < e) ? e : o;
  e = (low == up) ? mn : mx;
}

// sort one 1024-half of list A; 2 blocks per image -> 32 CUs busy, depth halved
__global__ __launch_bounds__(512) void sorthalf_kernel(
    const u32* __restrict__ cntA, const u64* __restrict__ candA,
    u64* __restrict__ sortA) {
  __shared__ u64 ping[1024], pong[1024];   // 16 KB
  int b = blockIdx.x >> 1, h = blockIdx.x & 1;
  int t = threadIdx.x, lane = t & 63;
  u32 S = cntA[b]; if (S > 2047u) S = 2047u;
  const u64* cA = candA + (size_t)b * PRE_NMS + h * 1024;
  u32 lim = (S > (u32)(h * 1024)) ? (S - (u32)(h * 1024)) : 0u;
  u64 e0 = ((u32)t < lim) ? cA[t] : ~0ull;
  u64 e1 = ((u32)(t + 512) < lim) ? cA[t + 512] : ~0ull;
  // bitonic 1024 ascending; thread owns elements (t, t+512)
  for (int k = 2; k <= 64; k <<= 1)
    for (int j = k >> 1; j >= 1; j >>= 1) {
      wave_ce(e0, t, k, j, lane);
      wave_ce(e1, t + 512, k, j, lane);
    }
  int pp = 0;
  for (int k = 128; k <= 1024; k <<= 1) {
    for (int j = k >> 1; j >= 64; j >>= 1) {
      if (j == 512) {
        reg_ce(e0, e1, true);              // k==1024 only: up for both halves
      } else {
        u64* buf = (pp & 1) ? pong : ping; ++pp;
        buf[t] = e0; buf[t + 512] = e1;
        __syncthreads();
        u64 o0 = buf[t ^ j];
        u64 o1 = buf[(t ^ j) + 512];
        bool low = ((t & j) == 0);
        lds_ce(e0, o0, low, ((t) & k) == 0);
        lds_ce(e1, o1, low, (((t + 512) & k)) == 0);
        // ping-pong: next LDS pass uses the other buffer (skew <= 1 barrier, safe)
      }
    }
    for (int j = 32; j >= 1; j >>= 1) {
      wave_ce(e0, t, k, j, lane);
      wave_ce(e1, t + 512, k, j, lane);
    }
  }
  u64* dst = sortA + (size_t)b * PRE_NMS + h * 1024;
  dst[t] = e0; dst[t + 512] = e1;
}

// merge halves + B-rank + decode + pipelined NMS chain + partition + output
__global__ __launch_bounds__(FTHR) void final_kernel(
    const float* __restrict__ delta, const float* __restrict__ anchor,
    const int* __restrict__ imgp,
    const u32* __restrict__ cntA, const u32* __restrict__ cntB,
    const u64* __restrict__ sortA, const u64* __restrict__ candB,
    float* __restrict__ out) {
  __shared__ u64 keys[PRE_NMS];        // 16 KB: sorted A halves, then B keys
  __shared__ u32 gpos[PRE_NMS];        // 8 KB
  __shared__ float2 box[PRE_NMS];      // 16 KB
  __shared__ u16 cpos[PRE_NMS];        // 4 KB
  __shared__ u32 bincnt[NSB], binstart[NSB + 1], binfill[NSB];
  __shared__ u32 supm[64];
  __shared__ float2 wboxD[2][64];
  __shared__ u32 wrangeD[2][64];
  __shared__ u32 nkeptD[2];
  __shared__ u32 LcntS;
  __shared__ u32 keepw[NCH * 2];
  __shared__ u32 wpre[65];

  int b = blockIdx.x, t = threadIdx.x;
  int wv = t >> 6, lane = t & 63;

  u32 S = cntA[b]; if (S > 2047u) S = 2047u;
  u32 T = cntB[b]; if (T > 2048u) T = 2048u;
  const u64* sA = sortA + (size_t)b * PRE_NMS;
  const u64* cB = candB + (size_t)b * PRE_NMS;

#pragma unroll
  for (int r = 0; r < 4; ++r) keys[t + 512 * r] = sA[t + 512 * r];
  __syncthreads();
  // merge the two sorted 1024-halves by rank (keys distinct; padding ~0 skipped)
#pragma unroll
  for (int r = 0; r < 4; ++r) {
    int p = t + 512 * r;
    u64 k = keys[p];
    if (k != ~0ull) {
      const u64* other = (p < 1024) ? (keys + 1024) : keys;
      u32 lo = 0, hi = 1024;
      while (lo < hi) { u32 mid = (lo + hi) >> 1; if (other[mid] < k) lo = mid + 1; else hi = mid; }
      gpos[(u32)(p & 1023) + lo] = (u32)k;   // rank < S < 2048 for valid keys
    }
  }
  __syncthreads();
  // B-list (cut bucket) fills positions [S, 2048)
  if (T <= 64u) {
    if (wv == 0) {
      u64 e = ((u32)lane < T) ? cB[lane] : ~0ull;
      for (int k = 2; k <= 64; k <<= 1)
        for (int j = k >> 1; j >= 1; j >>= 1)
          wave_ce(e, lane, k, j, lane);
      u32 pos = S + (u32)lane;
      if (pos < 2048u) gpos[pos] = (u32)e;
    }
  } else {
    // counting rank: O(T^2) compares, lockstep-broadcast LDS reads (T ~ hundreds)
    for (u32 p = t; p < 2048u; p += FTHR) keys[p] = (p < T) ? cB[p] : ~0ull;
    __syncthreads();
    for (u32 p = t; p < T; p += FTHR) {
      u64 k = keys[p];
      u32 cnt = 0;
      for (u32 q = 0; q < T; ++q) cnt += (keys[q] < k) ? 1u : 0u;
      u32 pos = S + cnt;
      if (pos < 2048u) gpos[pos] = (u32)k;
    }
  }
  __syncthreads();

  // decode + clip; thread owns positions t+512r  (chunk wv+8r, row lane)
  int iv = imgp[0];
  float img = (iv > 0 && iv < 1000000) ? (float)iv : __int_as_float(iv);
  float sbin = (float)NSB / img;
  const float2* d2 = (const float2*)delta;
  const float2* a2 = (const float2*)anchor;
  size_t base = (size_t)b * NELEM;
  float2 bx0 = decode_one(d2, a2, base, gpos[t], img);
  float2 bx1 = decode_one(d2, a2, base, gpos[t + 512], img);
  float2 bx2 = decode_one(d2, a2, base, gpos[t + 1024], img);
  float2 bx3 = decode_one(d2, a2, base, gpos[t + 1536], img);
  box[t] = bx0; box[t + 512] = bx1; box[t + 1024] = bx2; box[t + 1536] = bx3;
  if (t < NSB) { bincnt[t] = 0u; binfill[t] = 0u; }
  if (t < 64) supm[t] = 0u;
  if (t == 0) { LcntS = 0u; nkeptD[0] = 0u; nkeptD[1] = 0u; }
  float ca0 = __fmul_rn(0.5f, __fadd_rn(bx0.x, bx0.y));
  float ca1 = __fmul_rn(0.5f, __fadd_rn(bx1.x, bx1.y));
  float ca2 = __fmul_rn(0.5f, __fadd_rn(bx2.x, bx2.y));
  float ca3 = __fmul_rn(0.5f, __fadd_rn(bx3.x, bx3.y));
  int bi0 = (int)(ca0 * sbin); bi0 = bi0 > NSB - 1 ? NSB - 1 : bi0;
  int bi1 = (int)(ca1 * sbin); bi1 = bi1 > NSB - 1 ? NSB - 1 : bi1;
  int bi2 = (int)(ca2 * sbin); bi2 = bi2 > NSB - 1 ? NSB - 1 : bi2;
  int bi3 = (int)(ca3 * sbin); bi3 = bi3 > NSB - 1 ? NSB - 1 : bi3;
  __syncthreads();

  // spatial counting sort of candidate centers into 256 bins
  atomicAdd(&bincnt[bi0], 1u); atomicAdd(&bincnt[bi1], 1u);
  atomicAdd(&bincnt[bi2], 1u); atomicAdd(&bincnt[bi3], 1u);
  __syncthreads();
  if (wv == 0) {
    u32 c0 = bincnt[lane * 4 + 0], c1 = bincnt[lane * 4 + 1];
    u32 c2 = bincnt[lane * 4 + 2], c3 = bincnt[lane * 4 + 3];
    u32 ssum = c0 + c1 + c2 + c3;
    u32 inc = ssum;
    for (int d = 1; d < 64; d <<= 1) {
      u32 v = __shfl_up(inc, d);
      if (lane >= d) inc += v;
    }
    u32 excl = inc - ssum;
    binstart[lane * 4 + 0] = excl;
    binstart[lane * 4 + 1] = excl + c0;
    binstart[lane * 4 + 2] = excl + c0 + c1;
    binstart[lane * 4 + 3] = excl + c0 + c1 + c2;
    if (lane == 63) binstart[NSB] = inc;
  }
  __syncthreads();
  cpos[binstart[bi0] + atomicAdd(&binfill[bi0], 1u)] = (u16)t;
  cpos[binstart[bi1] + atomicAdd(&binfill[bi1], 1u)] = (u16)(t + 512);
  cpos[binstart[bi2] + atomicAdd(&binfill[bi2], 1u)] = (u16)(t + 1024);
  cpos[binstart[bi3] + atomicAdd(&binfill[bi3], 1u)] = (u16)(t + 1536);

  // in-chunk 64x64 exact adjacency rows, kept in registers
  u64 m0 = 0ull, m1 = 0ull, m2 = 0ull, m3 = 0ull;
  {
    float w0 = __fsub_rn(bx0.y, bx0.x), w1 = __fsub_rn(bx1.y, bx1.x);
    float w2 = __fsub_rn(bx2.y, bx2.x), w3 = __fsub_rn(bx3.y, bx3.x);
    int c0 = wv * 64, c1 = (wv + 8) * 64, c2 = (wv + 16) * 64, c3 = (wv + 24) * 64;
    for (int j = 0; j < 64; ++j) {
      float2 q0 = box[c0 + j], q1 = box[c1 + j], q2 = box[c2 + j], q3 = box[c3 + j];
      if ((j != lane) & iou_gt(bx0, w0, q0, __fsub_rn(q0.y, q0.x))) m0 |= 1ull << j;
      if ((j != lane) & iou_gt(bx1, w1, q1, __fsub_rn(q1.y, q1.x))) m1 |= 1ull << j;
      if ((j != lane) & iou_gt(bx2, w2, q2, __fsub_rn(q2.y, q2.x))) m2 |= 1ull << j;
      if ((j != lane) & iou_gt(bx3, w3, q3, __fsub_rn(q3.y, q3.x))) m3 |= 1ull << j;
    }
  }
  __syncthreads();   // cpos complete

  // ---- pipelined greedy NMS: ONE barrier per chunk ----
  // Invariant entering ch: supm has marks from kept of chunks <= ch-2;
  // wboxD[(ch-1)&1] holds kept of ch-1. Scan(ch) = supm + direct dense check of
  // kept_{ch-1} (independent broadcast loads -> pipelined). Other 7 waves mark
  // kept_{ch-1} into supm for chunks >= ch+1 (supm words disjoint from scan's).
  for (int ch = 0; ch < NCH; ++ch) {
    int par = ch & 1, ppar = par ^ 1;
    u32 nkp = nkeptD[ppar];
    int sc = ch & 7;
    if (wv == sc) {
      int r = ch >> 3;
      float2 myb = (r == 0) ? bx0 : (r == 1) ? bx1 : (r == 2) ? bx2 : bx3;
      u64 myrow = (r == 0) ? m0 : (r == 1) ? m1 : (r == 2) ? m2 : m3;
      float mywa = __fsub_rn(myb.y, myb.x);
      u32 supw = supm[ch * 2 + (lane >> 5)];
      bool mysup = (supw >> (lane & 31)) & 1u;
      for (u32 l = 0; l < nkp; ++l) {
        float2 kb = wboxD[ppar][l];
        mysup = mysup | iou_gt(myb, mywa, kb, __fsub_rn(kb.y, kb.x));
      }
      u64 s = __ballot(mysup);
      u64 rem = ~s;
      u64 kept = 0ull;
      u32 mlo = (u32)myrow, mhi = (u32)(myrow >> 32);
      while (rem) {                      // visit kept candidates only
        int i = __builtin_ctzll(rem);
        kept |= 1ull << i;
        u32 rlo = (u32)__builtin_amdgcn_readlane((int)mlo, i);
        u32 rhi = (u32)__builtin_amdgcn_readlane((int)mhi, i);
        u64 row = ((u64)rhi << 32) | (u64)rlo;
        rem &= ~(row | (1ull << i));
      }
      if ((kept >> lane) & 1ull) {
        // IoU>0.5 => suppressed center in [x1,x2]; +-0.25 margin absorbs all
        // f32 rounding + bin quantization (conservative; exact test re-applied)
        float cme_lo = fmaxf(__fsub_rn(myb.x, 0.25f), 0.0f);
        float cme_hi = __fadd_rn(myb.y, 0.25f);
        int blo = (int)(cme_lo * sbin); blo = blo > NSB - 1 ? NSB - 1 : blo;
        int bhi = (int)(cme_hi * sbin); bhi = bhi > NSB - 1 ? NSB - 1 : bhi;
        u32 lo = binstart[blo];
        u32 hi = binstart[bhi + 1];
        u32 li = (u32)__popcll(kept & ((1ull << lane) - 1ull));
        wboxD[par][li] = myb;
        wrangeD[par][li] = (lo << 16) | hi;
      }
      if (lane == 0) {
        keepw[ch * 2]     = (u32)kept;
        keepw[ch * 2 + 1] = (u32)(kept >> 32);
        nkeptD[par] = (u32)__popcll(kept);
        LcntS += (u32)__popcll(kept);
      }
    } else if (nkp) {
      u32 mwv = (u32)wv - ((wv > sc) ? 1u : 0u);   // 0..6
      u32 cmin = (u32)(ch + 1) * 64u;
      for (u32 k2 = mwv; k2 < nkp; k2 += 7u) {
        float2 kb = wboxD[ppar][k2];
        u32 rng = wrangeD[ppar][k2];
        u32 lo = rng >> 16, hi = rng & 0xFFFFu;
        float wbk = __fsub_rn(kb.y, kb.x);
        for (u32 idx = lo + (u32)lane; idx < hi; idx += 64u) {
          u32 p = cpos[idx];
          if (p >= cmin) {
            float2 bp = box[p];
            float wp = __fsub_rn(bp.y, bp.x);
            if (iou_gt(bp, wp, kb, wbk))
              atomicOr(&supm[p >> 5], 1u << (p & 31));
          }
        }
      }
    }
    __syncthreads();
    if (LcntS >= POST_NMS) {
      // outputs fully determined by the first 512 kept: zero undecided chunks
      int w2 = (ch + 1) * 2 + t;
      if (w2 < NCH * 2) keepw[w2] = 0u;
      break;
    }
  }
  __syncthreads();   // keepw zeroing (early-exit) visible

  // stable partition: kept first (ascending), then unkept (ascending)
  if (wv == 0) {
    u32 wvv = keepw[lane];
    u32 pc = __popc(wvv);
    u32 inc = pc;
    for (int d = 1; d < 64; d <<= 1) {
      u32 v = __shfl_up(inc, d);
      if (lane >= d) inc += v;
    }
    wpre[lane] = inc - pc;
    if (lane == 63) wpre[64] = inc;
  }
  __syncthreads();
  u32 K = wpre[64];
  size_t selOff = (size_t)BATCH * POST_NMS * 2;
  size_t valOff = selOff + (size_t)BATCH * POST_NMS;
#pragma unroll
  for (int r = 0; r < 4; ++r) {
    int p = t + FTHR * r;
    u32 w = p >> 5, bit = p & 31;
    u32 wvv = keepw[w];
    bool kp = (wvv >> bit) & 1u;
    u32 kpref = wpre[w] + __popc(wvv & ((1u << bit) - 1u));
    u32 rr = kp ? kpref : (K + ((u32)p - kpref));
    if (rr < POST_NMS) {
      float2 bxo = kp ? box[p] : make_float2(0.0f, 0.0f);
      size_t ob = (size_t)b * POST_NMS + rr;
      out[ob * 2 + 0] = bxo.x;
      out[ob * 2 + 1] = bxo.y;
      out[selOff + ob] = (float)p;
      out[valOff + ob] = kp ? 1.0f : 0.0f;
    }
  }
}

extern "C" void kernel_launch(void* const* d_in, const int* in_sizes, int n_in,
                              void* d_out, int out_size, void* d_ws, size_t ws_size,
                              hipStream_t stream) {
  const float* obj    = (const float*)d_in[0];
  const float* delta  = (const float*)d_in[1];
  const float* anchor = (const float*)d_in[2];
  const int*   imgp   = (const int*)d_in[3];
  float* out = (float*)d_out;

  unsigned char* w = (unsigned char*)d_ws;
  u32* hist  = (u32*)(w);
  u32* cntA  = (u32*)(w + OFF_CNTA);
  u32* cntB  = (u32*)(w + OFF_CNTB);
  u32* cutb  = (u32*)(w + OFF_CUT);
  u64* candA = (u64*)(w + OFF_CANDA);
  u64* candB = (u64*)(w + OFF_CANDB);
  u64* sortA = (u64*)(w + OFF_SORT);

  hipMemsetAsync(w, 0, OFF_CUT, stream);   // re-init hist + cnts every call

  hist_kernel<<<dim3(256), dim3(256), 0, stream>>>(obj, hist);
  cut_kernel<<<dim3(BATCH), dim3(256), 0, stream>>>(hist, cutb);
  collect_kernel<<<dim3(512), dim3(256), 0, stream>>>(obj, cutb, cntA, cntB, candA, candB);
  sorthalf_kernel<<<dim3(BATCH * 2), dim3(512), 0, stream>>>(cntA, candA, sortA);
  final_kernel<<<dim3(BATCH), dim3(FTHR), 0, stream>>>(delta, anchor, imgp,
                                                       cntA, cntB, sortA, candB, out);
}